// Round 1
// baseline (5211.322 us; speedup 1.0000x reference)
//
#include <hip/hip_runtime.h>
#include <math.h>

// ---------------- problem constants ----------------
#define B_    512
#define DIM   128
#define A_    3
#define C_    200000
#define K_    50
#define DELTA 1e-3

// ---------------- algorithm constants ----------------
#define NBIN  192      // piecewise-log bins: 16/octave, covers d2 in [0, 4095)
#define CAP   768      // max candidates per (b,a)
#define BM    64       // b rows per block in pass kernels
#define BN    128      // keys per inner tile
#define TPC   16       // tiles per chunk per block
#define CHUNK (TPC*BN) // 2048
#define NCH   ((C_ + CHUNK - 1)/CHUNK) // 98

// workspace layout (bytes)
#define OFF_H32   0u
#define OFF_H64   262144u
#define OFF_Q2    786432u
#define OFF_K2    788480u
#define OFF_HIST  3188480u
#define OFF_TAU   4368128u
#define OFF_CNT   4374272u
#define OFF_V64   4380416u
#define OFF_CAND  4392704u
// total ~9.12 MB

// ============ kernel 1: MLP encoder (fp64 to match np-f64 ref) ============
__global__ __launch_bounds__(128) void mlp_kernel(
    const float* __restrict__ x,
    const float* __restrict__ W1, const float* __restrict__ b1,
    const float* __restrict__ W2, const float* __restrict__ b2,
    const float* __restrict__ W3, const float* __restrict__ b3,
    const float* __restrict__ W4, const float* __restrict__ b4,
    float* __restrict__ h32, double* __restrict__ h64, float* __restrict__ q2)
{
    int b = blockIdx.x, t = threadIdx.x;
    __shared__ double s0[DIM], s1[DIM];
    double x0 = (double)x[b*2+0], x1 = (double)x[b*2+1];
    double h = x0*(double)W1[t] + x1*(double)W1[DIM+t] + (double)b1[t];
    s0[t] = h > 0.0 ? h : 0.0;
    __syncthreads();
    double acc = (double)b2[t];
    for (int k = 0; k < DIM; k++) acc += s0[k]*(double)W2[k*DIM+t];
    s1[t] = acc > 0.0 ? acc : 0.0;
    __syncthreads();
    acc = (double)b3[t];
    for (int k = 0; k < DIM; k++) acc += s1[k]*(double)W3[k*DIM+t];
    s0[t] = acc > 0.0 ? acc : 0.0;
    __syncthreads();
    acc = (double)b4[t];
    for (int k = 0; k < DIM; k++) acc += s0[k]*(double)W4[k*DIM+t];
    h64[b*DIM+t] = acc;
    h32[b*DIM+t] = (float)acc;
    s1[t] = acc*acc;
    __syncthreads();
    for (int s = 64; s > 0; s >>= 1) { if (t < s) s1[t] += s1[t+s]; __syncthreads(); }
    if (t == 0) q2[b] = (float)s1[0];
}

// ============ kernel 2: per-key squared norms (wave per row) ============
__global__ __launch_bounds__(256) void k2_kernel(const float* __restrict__ keys,
                                                 float* __restrict__ k2)
{
    int r = blockIdx.x*4 + (threadIdx.x >> 6);
    int lane = threadIdx.x & 63;
    float2 v = ((const float2*)keys)[(size_t)r*64 + lane];
    float s = v.x*v.x + v.y*v.y;
    #pragma unroll
    for (int off = 32; off > 0; off >>= 1) s += __shfl_down(s, off, 64);
    if (lane == 0) k2[r] = s;
}

// ============ kernels 3 & 5: tiled fp32 distance GEMM ============
// MODE 0: build per-(b,a) histogram of d2.  MODE 1: collect candidates d2<tau.
// LDS tiles stored as [row][kq] float4 with row stride 33 (f4 units) for
// bank-spread; thread's 4 n are strided n = j*32+tx so consecutive lanes read
// consecutive rows (4 lanes/bank on ks reads = minimal phases for b128).
template<int MODE>
__global__ __launch_bounds__(256) void pass_kernel(
    const float* __restrict__ keys, const float* __restrict__ h32,
    const float* __restrict__ q2,   const float* __restrict__ k2,
    unsigned* __restrict__ hist,    const float* __restrict__ tau,
    unsigned* __restrict__ cnt,     int* __restrict__ cand)
{
    const int bt = blockIdx.x;       // b tile (0..7)
    const int ch = blockIdx.y;       // chunk (0..NCH-1)
    const int a  = blockIdx.z;       // action (0..2)
    const int b0 = bt*BM;
    const int tid = threadIdx.x;
    const int tx = tid & 31, ty = tid >> 5;

    __shared__ float4 hs4[BM*33];          // [b][kq]
    __shared__ float4 ks4[BN*33];          // [n][kq]
    __shared__ float  q2s[BM];
    __shared__ float  taus[BM];
    __shared__ unsigned hist_s[MODE == 0 ? BM*NBIN : 1];

    // h tile: BM*32 f4 = 2048, 8 per thread
    #pragma unroll
    for (int q = 0; q < BM*32/256; q++) {
        int flat = q*256 + tid; int row = flat >> 5, kq = flat & 31;
        hs4[row*33 + kq] = ((const float4*)h32)[(size_t)(b0+row)*32 + kq];
    }
    if (tid < BM) {
        q2s[tid] = q2[b0+tid];
        if (MODE == 1) taus[tid] = tau[(b0+tid)*A_ + a];
    }
    if (MODE == 0) for (int i = tid; i < BM*NBIN; i += 256) hist_s[i] = 0;
    const float* __restrict__ k2g = k2 + (size_t)a*C_;

    for (int t = 0; t < TPC; t++) {
        int n0 = ch*CHUNK + t*BN;
        if (n0 >= C_) break;
        __syncthreads();  // previous tile's reads done (also covers init)
        // keys tile: BN*32 f4 = 4096, 16/thread, coalesced global reads
        #pragma unroll
        for (int q = 0; q < 16; q++) {
            int flat = q*256 + tid; int row = flat >> 5, kq = flat & 31;
            int nr = n0 + row; if (nr >= C_) nr = C_-1;
            ks4[row*33 + kq] = ((const float4*)keys)[((size_t)a*C_ + nr)*32 + kq];
        }
        __syncthreads();

        float acc[8][4];
        #pragma unroll
        for (int i = 0; i < 8; i++)
            #pragma unroll
            for (int j = 0; j < 4; j++) acc[i][j] = 0.0f;

        for (int kq = 0; kq < 32; kq++) {
            float4 hv[8], kv[4];
            #pragma unroll
            for (int i = 0; i < 8; i++) hv[i] = hs4[(ty*8+i)*33 + kq];
            #pragma unroll
            for (int j = 0; j < 4; j++) kv[j] = ks4[(j*32+tx)*33 + kq];
            #pragma unroll
            for (int i = 0; i < 8; i++)
                #pragma unroll
                for (int j = 0; j < 4; j++)
                    acc[i][j] += hv[i].x*kv[j].x + hv[i].y*kv[j].y
                               + hv[i].z*kv[j].z + hv[i].w*kv[j].w;
        }

        // epilogue: d2 = q2 + k2 - 2*cross
        #pragma unroll
        for (int i = 0; i < 8; i++) {
            int bl = ty*8 + i;
            float q2b = q2s[bl];
            #pragma unroll
            for (int j = 0; j < 4; j++) {
                int n = n0 + j*32 + tx;
                if (n < C_) {
                    float d2f = fmaxf(q2b + k2g[n] - 2.0f*acc[i][j], 0.0f);
                    if (MODE == 0) {
                        int bin = (int)(__float_as_uint(d2f + 1.0f) >> 19) - 2032;
                        bin = bin < 0 ? 0 : (bin > NBIN-1 ? NBIN-1 : bin);
                        atomicAdd(&hist_s[bl*NBIN + bin], 1u);
                    } else {
                        if (d2f < taus[bl]) {
                            int p = (b0+bl)*A_ + a;
                            unsigned pos = atomicAdd(&cnt[p], 1u);
                            if (pos < CAP) cand[(size_t)p*CAP + pos] = n;
                        }
                    }
                }
            }
        }
    }
    if (MODE == 0) {
        __syncthreads();
        for (int i = tid; i < BM*NBIN; i += 256) {
            unsigned v = hist_s[i];
            if (v) {
                int bl = i / NBIN, bin = i % NBIN;
                atomicAdd(&hist[(size_t)((b0+bl)*A_ + a)*NBIN + bin], v);
            }
        }
    }
}

// ============ kernel 4: threshold from histogram ============
__global__ __launch_bounds__(256) void tau_kernel(const unsigned* __restrict__ hist,
                                                  float* __restrict__ tau)
{
    int p = blockIdx.x*256 + threadIdx.x;
    if (p >= B_*A_) return;
    const unsigned* hp = hist + (size_t)p*NBIN;
    unsigned cum = 0; int jsel = NBIN-1;
    for (int j = 0; j < NBIN; j++) { cum += hp[j]; if (cum >= K_) { jsel = j; break; } }
    // upper edge of bin jsel+1 (one-bin slack)
    tau[p] = __uint_as_float((unsigned)(2034 + jsel) << 19) - 1.0f;
}

// ============ kernel 6: exact fp64 top-K + NEC weighted value ============
__global__ __launch_bounds__(256) void select_kernel(
    const float* __restrict__ keys, const double* __restrict__ h64,
    const float* __restrict__ mem_values,
    const unsigned* __restrict__ cnt, const int* __restrict__ cand,
    float* __restrict__ out_values, double* __restrict__ val64)
{
    int p = blockIdx.x; int b = p / A_, a = p % A_;
    int tid = threadIdx.x;
    __shared__ double hd[DIM];
    __shared__ double d2s[CAP];
    __shared__ float  vs[CAP];
    __shared__ double red[256];
    __shared__ int    redi[256];
    __shared__ double acc_w, acc_wv;

    for (int i = tid; i < DIM; i += 256) hd[i] = h64[(size_t)b*DIM + i];
    if (tid == 0) { acc_w = 0.0; acc_wv = 0.0; }
    __syncthreads();

    int n = (int)cnt[p]; if (n > CAP) n = CAP;
    for (int i = tid; i < n; i += 256) {
        int c = cand[(size_t)p*CAP + i];
        const float4* kr = (const float4*)(keys + ((size_t)a*C_ + c)*DIM);
        double s0 = 0.0, s1 = 0.0;
        #pragma unroll 4
        for (int kq = 0; kq < 32; kq++) {
            float4 kv = kr[kq];
            double d0 = hd[4*kq+0] - (double)kv.x;
            double d1 = hd[4*kq+1] - (double)kv.y;
            double d2 = hd[4*kq+2] - (double)kv.z;
            double d3 = hd[4*kq+3] - (double)kv.w;
            s0 += d0*d0 + d1*d1; s1 += d2*d2 + d3*d3;
        }
        d2s[i] = s0 + s1;
        vs[i]  = mem_values[(size_t)a*C_ + c];
    }
    __syncthreads();

    int kk = n < K_ ? n : K_;
    for (int t = 0; t < kk; t++) {
        double best = 1e300; int bi = -1;
        for (int i = tid; i < n; i += 256)
            if (d2s[i] < best) { best = d2s[i]; bi = i; }
        red[tid] = best; redi[tid] = bi;
        __syncthreads();
        for (int s = 128; s > 0; s >>= 1) {
            if (tid < s && red[tid+s] < red[tid]) { red[tid] = red[tid+s]; redi[tid] = redi[tid+s]; }
            __syncthreads();
        }
        if (tid == 0) {
            int wi = redi[0];
            double d = d2s[wi]; if (d < 0.0) d = 0.0;
            double w = 1.0 / (d + DELTA);
            acc_w += w; acc_wv += w * (double)vs[wi];
            d2s[wi] = 2e300;
        }
        __syncthreads();
    }
    if (tid == 0) {
        double v = acc_wv / acc_w;
        out_values[p] = (float)v;
        val64[p] = v;
    }
}

// ============ kernel 7: argmax over actions ============
__global__ void argmax_kernel(const double* __restrict__ val64, float* __restrict__ out)
{
    int b = blockIdx.x*blockDim.x + threadIdx.x;
    if (b >= B_) return;
    double v0 = val64[b*A_+0], v1 = val64[b*A_+1], v2 = val64[b*A_+2];
    int bi = 0; double bv = v0;
    if (v1 > bv) { bv = v1; bi = 1; }
    if (v2 > bv) { bv = v2; bi = 2; }
    out[B_*A_ + b] = (float)bi;   // actions appended after values [512,3]
}

// ============ host ============
extern "C" void kernel_launch(void* const* d_in, const int* in_sizes, int n_in,
                              void* d_out, int out_size, void* d_ws, size_t ws_size,
                              hipStream_t stream)
{
    const float* x   = (const float*)d_in[0];
    const float* W1  = (const float*)d_in[1];
    const float* b1  = (const float*)d_in[2];
    const float* W2  = (const float*)d_in[3];
    const float* b2  = (const float*)d_in[4];
    const float* W3  = (const float*)d_in[5];
    const float* b3  = (const float*)d_in[6];
    const float* W4  = (const float*)d_in[7];
    const float* b4  = (const float*)d_in[8];
    const float* keys = (const float*)d_in[9];
    const float* memv = (const float*)d_in[10];

    char* ws = (char*)d_ws;
    float*    h32  = (float*)   (ws + OFF_H32);
    double*   h64  = (double*)  (ws + OFF_H64);
    float*    q2   = (float*)   (ws + OFF_Q2);
    float*    k2   = (float*)   (ws + OFF_K2);
    unsigned* hist = (unsigned*)(ws + OFF_HIST);
    float*    tau  = (float*)   (ws + OFF_TAU);
    unsigned* cnt  = (unsigned*)(ws + OFF_CNT);
    double*   val64= (double*)  (ws + OFF_V64);
    int*      cand = (int*)     (ws + OFF_CAND);

    // zero hist + tau + cnt (ws is poisoned 0xAA before every launch)
    hipMemsetAsync(ws + OFF_HIST, 0, (OFF_CNT + B_*A_*4) - OFF_HIST, stream);

    mlp_kernel<<<B_, 128, 0, stream>>>(x, W1, b1, W2, b2, W3, b3, W4, b4, h32, h64, q2);
    k2_kernel<<<(A_*C_)/4, 256, 0, stream>>>(keys, k2);
    pass_kernel<0><<<dim3(B_/BM, NCH, A_), 256, 0, stream>>>(keys, h32, q2, k2, hist, nullptr, nullptr, nullptr);
    tau_kernel<<<(B_*A_ + 255)/256, 256, 0, stream>>>(hist, tau);
    pass_kernel<1><<<dim3(B_/BM, NCH, A_), 256, 0, stream>>>(keys, h32, q2, k2, nullptr, tau, cnt, cand);
    select_kernel<<<B_*A_, 256, 0, stream>>>(keys, h64, memv, cnt, cand, (float*)d_out, val64);
    argmax_kernel<<<2, 256, 0, stream>>>(val64, (float*)d_out);
}

// Round 2
// 1061.023 us; speedup vs baseline: 4.9116x; 4.9116x over previous
//
#include <hip/hip_runtime.h>
#include <hip/hip_bf16.h>
#include <math.h>

// ---------------- problem constants ----------------
#define B_    512
#define DIM   128
#define A_    3
#define C_    200000
#define K_    50
#define DELTA 1e-3

typedef __attribute__((ext_vector_type(8))) short bf16x8;
typedef __attribute__((ext_vector_type(4))) float f32x4;

// ---------------- Path A (MFMA + u8 bin matrix) constants ----------------
#define NBIN_A 128          // 16 bins/octave over d2 in [16,4096)
#define CAP_A  1024
#define NSEG_G 128          // gemm grid.x
#define TPS_G  13           // N-tiles per segment (128*13 = 1664 >= 1563)
#define NT_G   1563         // ceil(200000/128)
#define HSEG   16           // hist/collect segments per (b,a) row
#define CHPS   782          // 16B chunks per segment (16*782 = 12512 >= 12500)
#define ROWCH  12500        // 16B chunks per row (200000/16)

// Path A ws offsets (bytes)
#define AOFF_H64   0u
#define AOFF_H32   524288u
#define AOFF_HBF   786432u
#define AOFF_Q2    917504u
#define AOFF_HIST  919552u
#define AOFF_CNT   1705984u
#define AOFF_TAUB  1712128u
#define AOFF_V64   1718272u
#define AOFF_CAND  1730560u
#define AOFF_BINS  8022016u
#define NEED_A     (8022016ull + 307200000ull)   // ~315.2 MB

// ---------------- Path B (round-1 fallback) constants ----------------
#define NBIN_B 192
#define CAP_B  768
#define BM_B   64
#define BN_B   128
#define TPC_B  16
#define CHUNK_B (TPC_B*BN_B)
#define NCH_B  ((C_ + CHUNK_B - 1)/CHUNK_B)

#define BOFF_H32   0u
#define BOFF_H64   262144u
#define BOFF_Q2    786432u
#define BOFF_K2    788480u
#define BOFF_HIST  3188480u
#define BOFF_TAU   4368128u
#define BOFF_CNT   4374272u
#define BOFF_V64   4380416u
#define BOFF_CAND  4392704u

static __device__ inline unsigned short f2bf(float x) {
    union { float f; unsigned u; } c; c.f = x;
    unsigned r = (c.u + 0x7FFFu + ((c.u >> 16) & 1u)) >> 16;
    return (unsigned short)r;
}
static __device__ inline unsigned pkbf(float a, float b) {
    __hip_bfloat162 t = __float22bfloat162_rn(make_float2(a, b));
    union { __hip_bfloat162 h; unsigned u; } cv; cv.h = t; return cv.u;
}

// ============ MLP encoder (fp64, matches np-f64 ref) ============
__global__ __launch_bounds__(128) void mlp_kernel(
    const float* __restrict__ x,
    const float* __restrict__ W1, const float* __restrict__ b1,
    const float* __restrict__ W2, const float* __restrict__ b2,
    const float* __restrict__ W3, const float* __restrict__ b3,
    const float* __restrict__ W4, const float* __restrict__ b4,
    float* __restrict__ h32, unsigned short* __restrict__ hbf,
    double* __restrict__ h64, float* __restrict__ q2)
{
    int b = blockIdx.x, t = threadIdx.x;
    __shared__ double s0[DIM], s1[DIM];
    double x0 = (double)x[b*2+0], x1 = (double)x[b*2+1];
    double h = x0*(double)W1[t] + x1*(double)W1[DIM+t] + (double)b1[t];
    s0[t] = h > 0.0 ? h : 0.0;
    __syncthreads();
    double acc = (double)b2[t];
    for (int k = 0; k < DIM; k++) acc += s0[k]*(double)W2[k*DIM+t];
    s1[t] = acc > 0.0 ? acc : 0.0;
    __syncthreads();
    acc = (double)b3[t];
    for (int k = 0; k < DIM; k++) acc += s1[k]*(double)W3[k*DIM+t];
    s0[t] = acc > 0.0 ? acc : 0.0;
    __syncthreads();
    acc = (double)b4[t];
    for (int k = 0; k < DIM; k++) acc += s0[k]*(double)W4[k*DIM+t];
    h64[b*DIM+t] = acc;
    float hf = (float)acc;
    h32[b*DIM+t] = hf;
    hbf[b*DIM+t] = f2bf(hf);
    s1[t] = acc*acc;
    __syncthreads();
    for (int s = 64; s > 0; s >>= 1) { if (t < s) s1[t] += s1[t+s]; __syncthreads(); }
    if (t == 0) q2[b] = (float)s1[0];
}

// ============ Path A: bf16 MFMA distance GEMM -> u8 log-bins ============
// 128x128 tile, 4 waves (each 64x64 via 4x4 of 16x16x32 MFMA), K=128 in LDS.
// LDS rows padded to 136 shorts (272 B) -> frag ds_read_b128 is 2-way (free).
// B tile: fp32 keys staged via VGPR roundtrip w/ packed bf16 convert; k2 fused.
__global__ __launch_bounds__(256, 2) void gemm_bin_kernel(
    const float* __restrict__ keys, const unsigned short* __restrict__ hbf,
    const float* __restrict__ q2, unsigned char* __restrict__ bins)
{
    const int seg = blockIdx.x, my = blockIdx.y, a = blockIdx.z;
    const int b0 = my*128;
    const int tid = threadIdx.x;
    const int lane = tid & 63, w = tid >> 6;
    const int lm = lane & 15, kh = lane >> 4;
    const int wm = w & 1, wn = w >> 1;

    __shared__ short sA[128*136];
    __shared__ short sB[128*136];
    __shared__ float q2s[128];
    __shared__ float k2s[128];

    // stage A (h_bf rows) once
    {
        int r = tid >> 1, hh = tid & 1;
        const int4* gp = (const int4*)hbf + (size_t)(b0 + r)*16 + hh*8;
        int4* dp = (int4*)&sA[r*136 + hh*64];
        #pragma unroll
        for (int q = 0; q < 8; q++) dp[q] = gp[q];
        if (tid < 128) q2s[tid] = q2[b0 + tid];
    }

    for (int t = 0; t < TPS_G; t++) {
        int nt = seg*TPS_G + t;
        if (nt >= NT_G) break;
        int n0 = nt*128;
        __syncthreads();   // prev tile's LDS reads done (also covers A-stage)
        // stage B: fp32 keys -> bf16 LDS, fused fp32 k2
        {
            int r = tid >> 1, hh = tid & 1;
            int nr = n0 + r; if (nr >= C_) nr = C_-1;
            const float4* gp = (const float4*)(keys + ((size_t)a*C_ + nr)*128) + hh*16;
            float ss = 0.0f;
            int4* dp = (int4*)&sB[r*136 + hh*64];
            #pragma unroll
            for (int q = 0; q < 8; q++) {
                float4 v0 = gp[2*q], v1 = gp[2*q+1];
                ss += v0.x*v0.x + v0.y*v0.y + v0.z*v0.z + v0.w*v0.w
                    + v1.x*v1.x + v1.y*v1.y + v1.z*v1.z + v1.w*v1.w;
                int4 pk;
                pk.x = (int)pkbf(v0.x, v0.y);
                pk.y = (int)pkbf(v0.z, v0.w);
                pk.z = (int)pkbf(v1.x, v1.y);
                pk.w = (int)pkbf(v1.z, v1.w);
                dp[q] = pk;
            }
            ss += __shfl_xor(ss, 1, 64);
            if (hh == 0) k2s[r] = ss;
        }
        __syncthreads();

        f32x4 acc[4][4];
        #pragma unroll
        for (int i = 0; i < 4; i++)
            #pragma unroll
            for (int j = 0; j < 4; j++) acc[i][j] = (f32x4){0.f, 0.f, 0.f, 0.f};

        #pragma unroll
        for (int kst = 0; kst < 4; kst++) {
            bf16x8 af[4], bfv[4];
            #pragma unroll
            for (int i = 0; i < 4; i++)
                af[i] = *(const bf16x8*)&sA[(wm*64 + i*16 + lm)*136 + kst*32 + kh*8];
            #pragma unroll
            for (int j = 0; j < 4; j++)
                bfv[j] = *(const bf16x8*)&sB[(wn*64 + j*16 + lm)*136 + kst*32 + kh*8];
            #pragma unroll
            for (int i = 0; i < 4; i++)
                #pragma unroll
                for (int j = 0; j < 4; j++)
                    acc[i][j] = __builtin_amdgcn_mfma_f32_16x16x32_bf16(af[i], bfv[j], acc[i][j], 0, 0, 0);
        }

        // epilogue: d2 = q2 + k2 - 2*cross -> u8 log-bin
        unsigned char* bp = bins + ((size_t)(a*B_ + b0))*C_ + n0;
        #pragma unroll
        for (int j = 0; j < 4; j++) {
            int col = wn*64 + j*16 + lm;
            int n = n0 + col;
            if (n < C_) {
                float kk = k2s[col];
                #pragma unroll
                for (int i = 0; i < 4; i++) {
                    int rl = wm*64 + i*16 + kh*4;
                    #pragma unroll
                    for (int reg = 0; reg < 4; reg++) {
                        float d2v = q2s[rl+reg] + kk - 2.0f*acc[i][j][reg];
                        float dc = fminf(fmaxf(d2v, 16.0f), 4095.0f);
                        int bin = (int)(__float_as_uint(dc) >> 19) - 2096;
                        bp[(size_t)(rl+reg)*C_ + col] = (unsigned char)bin;
                    }
                }
            }
        }
    }
}

// ============ Path A: streaming histogram over u8 bins ============
__global__ __launch_bounds__(256) void histA_kernel(const unsigned char* __restrict__ bins,
                                                    unsigned* __restrict__ hist)
{
    int q = blockIdx.x;            // a*B_ + b
    int seg = blockIdx.y;
    int tid = threadIdx.x;
    int a = q >> 9, b = q & 511;
    int p = b*A_ + a;
    __shared__ unsigned hs[NBIN_A*8];   // 8 replicas to spread same-bin atomics
    for (int i = tid; i < NBIN_A*8; i += 256) hs[i] = 0;
    __syncthreads();
    const uint4* row = (const uint4*)(bins + (size_t)q*C_);
    int ch0 = seg*CHPS, ch1 = ch0 + CHPS; if (ch1 > ROWCH) ch1 = ROWCH;
    int rep = tid & 7;
    for (int ch = ch0 + tid; ch < ch1; ch += 256) {
        uint4 v = row[ch];
        unsigned d[4] = {v.x, v.y, v.z, v.w};
        #pragma unroll
        for (int e = 0; e < 4; e++) {
            unsigned x = d[e];
            atomicAdd(&hs[((x      ) & 127u)*8 + rep], 1u);
            atomicAdd(&hs[((x >>  8) & 127u)*8 + rep], 1u);
            atomicAdd(&hs[((x >> 16) & 127u)*8 + rep], 1u);
            atomicAdd(&hs[((x >> 24) & 127u)*8 + rep], 1u);
        }
    }
    __syncthreads();
    if (tid < NBIN_A) {
        unsigned s = 0;
        #pragma unroll
        for (int r2 = 0; r2 < 8; r2++) s += hs[tid*8 + r2];
        if (s) atomicAdd(&hist[(size_t)p*NBIN_A + tid], s);
    }
}

// ============ Path A: threshold bin ============
__global__ void tauA_kernel(const unsigned* __restrict__ hist, int* __restrict__ taubin)
{
    int p = blockIdx.x*256 + threadIdx.x;
    if (p >= B_*A_) return;
    const unsigned* hp = hist + (size_t)p*NBIN_A;
    unsigned cum = 0; int jsel = NBIN_A-1;
    for (int j = 0; j < NBIN_A; j++) { cum += hp[j]; if (cum >= K_) { jsel = j; break; } }
    unsigned c1 = cum + (jsel+1 < NBIN_A ? hp[jsel+1] : 0u);
    unsigned c2 = c1  + (jsel+2 < NBIN_A ? hp[jsel+2] : 0u);
    int jt = (c2 <= 768u) ? jsel+2 : jsel+1;   // >= jsel+1 always (capture margin)
    if (jt > NBIN_A-1) jt = NBIN_A-1;
    taubin[p] = jt;
}

// ============ Path A: streaming candidate collect ============
__global__ __launch_bounds__(256) void collectA_kernel(const unsigned char* __restrict__ bins,
    const int* __restrict__ taubin, unsigned* __restrict__ cnt, int* __restrict__ cand)
{
    int q = blockIdx.x, seg = blockIdx.y, tid = threadIdx.x;
    int a = q >> 9, b = q & 511;
    int p = b*A_ + a;
    int tb = taubin[p];
    unsigned thr  = (unsigned)(tb + 1);           // select bytes < thr (<= tb)
    unsigned addv = (128u - thr) * 0x01010101u;   // bit7 set iff byte >= thr
    const uint4* row = (const uint4*)(bins + (size_t)q*C_);
    int ch0 = seg*CHPS, ch1 = ch0 + CHPS; if (ch1 > ROWCH) ch1 = ROWCH;
    for (int ch = ch0 + tid; ch < ch1; ch += 256) {
        uint4 v = row[ch];
        unsigned d[4] = {v.x, v.y, v.z, v.w};
        #pragma unroll
        for (int e = 0; e < 4; e++) {
            unsigned m = (d[e] + addv) & 0x80808080u;
            if (m != 0x80808080u) {
                #pragma unroll
                for (int by = 0; by < 4; by++) {
                    if (!((m >> (8*by + 7)) & 1u)) {
                        int n = ch*16 + e*4 + by;
                        unsigned pos = atomicAdd(&cnt[p], 1u);
                        if (pos < CAP_A) cand[(size_t)p*CAP_A + pos] = n;
                    }
                }
            }
        }
    }
}

// ============ Path B (round-1 fallback) kernels ============
__global__ __launch_bounds__(256) void k2_kernel(const float* __restrict__ keys,
                                                 float* __restrict__ k2)
{
    int r = blockIdx.x*4 + (threadIdx.x >> 6);
    int lane = threadIdx.x & 63;
    float2 v = ((const float2*)keys)[(size_t)r*64 + lane];
    float s = v.x*v.x + v.y*v.y;
    #pragma unroll
    for (int off = 32; off > 0; off >>= 1) s += __shfl_down(s, off, 64);
    if (lane == 0) k2[r] = s;
}

template<int MODE>
__global__ __launch_bounds__(256) void pass_kernel(
    const float* __restrict__ keys, const float* __restrict__ h32,
    const float* __restrict__ q2,   const float* __restrict__ k2,
    unsigned* __restrict__ hist,    const float* __restrict__ tau,
    unsigned* __restrict__ cnt,     int* __restrict__ cand)
{
    const int bt = blockIdx.x;
    const int ch = blockIdx.y;
    const int a  = blockIdx.z;
    const int b0 = bt*BM_B;
    const int tid = threadIdx.x;
    const int tx = tid & 31, ty = tid >> 5;

    __shared__ float4 hs4[BM_B*33];
    __shared__ float4 ks4[BN_B*33];
    __shared__ float  q2s[BM_B];
    __shared__ float  taus[BM_B];
    __shared__ unsigned hist_s[MODE == 0 ? BM_B*NBIN_B : 1];

    #pragma unroll
    for (int q = 0; q < BM_B*32/256; q++) {
        int flat = q*256 + tid; int row = flat >> 5, kq = flat & 31;
        hs4[row*33 + kq] = ((const float4*)h32)[(size_t)(b0+row)*32 + kq];
    }
    if (tid < BM_B) {
        q2s[tid] = q2[b0+tid];
        if (MODE == 1) taus[tid] = tau[(b0+tid)*A_ + a];
    }
    if (MODE == 0) for (int i = tid; i < BM_B*NBIN_B; i += 256) hist_s[i] = 0;
    const float* __restrict__ k2g = k2 + (size_t)a*C_;

    for (int t = 0; t < TPC_B; t++) {
        int n0 = ch*CHUNK_B + t*BN_B;
        if (n0 >= C_) break;
        __syncthreads();
        #pragma unroll
        for (int q = 0; q < 16; q++) {
            int flat = q*256 + tid; int row = flat >> 5, kq = flat & 31;
            int nr = n0 + row; if (nr >= C_) nr = C_-1;
            ks4[row*33 + kq] = ((const float4*)keys)[((size_t)a*C_ + nr)*32 + kq];
        }
        __syncthreads();

        float acc[8][4];
        #pragma unroll
        for (int i = 0; i < 8; i++)
            #pragma unroll
            for (int j = 0; j < 4; j++) acc[i][j] = 0.0f;

        for (int kq = 0; kq < 32; kq++) {
            float4 hv[8], kv[4];
            #pragma unroll
            for (int i = 0; i < 8; i++) hv[i] = hs4[(ty*8+i)*33 + kq];
            #pragma unroll
            for (int j = 0; j < 4; j++) kv[j] = ks4[(j*32+tx)*33 + kq];
            #pragma unroll
            for (int i = 0; i < 8; i++)
                #pragma unroll
                for (int j = 0; j < 4; j++)
                    acc[i][j] += hv[i].x*kv[j].x + hv[i].y*kv[j].y
                               + hv[i].z*kv[j].z + hv[i].w*kv[j].w;
        }

        #pragma unroll
        for (int i = 0; i < 8; i++) {
            int bl = ty*8 + i;
            float q2b = q2s[bl];
            #pragma unroll
            for (int j = 0; j < 4; j++) {
                int n = n0 + j*32 + tx;
                if (n < C_) {
                    float d2f = fmaxf(q2b + k2g[n] - 2.0f*acc[i][j], 0.0f);
                    if (MODE == 0) {
                        int bin = (int)(__float_as_uint(d2f + 1.0f) >> 19) - 2032;
                        bin = bin < 0 ? 0 : (bin > NBIN_B-1 ? NBIN_B-1 : bin);
                        atomicAdd(&hist_s[bl*NBIN_B + bin], 1u);
                    } else {
                        if (d2f < taus[bl]) {
                            int p = (b0+bl)*A_ + a;
                            unsigned pos = atomicAdd(&cnt[p], 1u);
                            if (pos < CAP_B) cand[(size_t)p*CAP_B + pos] = n;
                        }
                    }
                }
            }
        }
    }
    if (MODE == 0) {
        __syncthreads();
        for (int i = tid; i < BM_B*NBIN_B; i += 256) {
            unsigned v = hist_s[i];
            if (v) {
                int bl = i / NBIN_B, bin = i % NBIN_B;
                atomicAdd(&hist[(size_t)((b0+bl)*A_ + a)*NBIN_B + bin], v);
            }
        }
    }
}

__global__ __launch_bounds__(256) void tauB_kernel(const unsigned* __restrict__ hist,
                                                   float* __restrict__ tau)
{
    int p = blockIdx.x*256 + threadIdx.x;
    if (p >= B_*A_) return;
    const unsigned* hp = hist + (size_t)p*NBIN_B;
    unsigned cum = 0; int jsel = NBIN_B-1;
    for (int j = 0; j < NBIN_B; j++) { cum += hp[j]; if (cum >= K_) { jsel = j; break; } }
    tau[p] = __uint_as_float((unsigned)(2034 + jsel) << 19) - 1.0f;
}

// ============ shared: exact fp64 top-K + NEC weighted value ============
__global__ __launch_bounds__(256) void select_kernel(
    const float* __restrict__ keys, const double* __restrict__ h64,
    const float* __restrict__ mem_values,
    const unsigned* __restrict__ cnt, const int* __restrict__ cand,
    float* __restrict__ out_values, double* __restrict__ val64, int cap)
{
    int p = blockIdx.x; int b = p / A_, a = p % A_;
    int tid = threadIdx.x;
    __shared__ double hd[DIM];
    __shared__ double d2s[CAP_A];
    __shared__ float  vs[CAP_A];
    __shared__ double red[256];
    __shared__ int    redi[256];
    __shared__ double acc_w, acc_wv;

    for (int i = tid; i < DIM; i += 256) hd[i] = h64[(size_t)b*DIM + i];
    if (tid == 0) { acc_w = 0.0; acc_wv = 0.0; }
    __syncthreads();

    int n = (int)cnt[p]; if (n > cap) n = cap;
    for (int i = tid; i < n; i += 256) {
        int c = cand[(size_t)p*cap + i];
        const float4* kr = (const float4*)(keys + ((size_t)a*C_ + c)*DIM);
        double s0 = 0.0, s1 = 0.0;
        #pragma unroll 4
        for (int kq = 0; kq < 32; kq++) {
            float4 kv = kr[kq];
            double d0 = hd[4*kq+0] - (double)kv.x;
            double d1 = hd[4*kq+1] - (double)kv.y;
            double d2 = hd[4*kq+2] - (double)kv.z;
            double d3 = hd[4*kq+3] - (double)kv.w;
            s0 += d0*d0 + d1*d1; s1 += d2*d2 + d3*d3;
        }
        d2s[i] = s0 + s1;
        vs[i]  = mem_values[(size_t)a*C_ + c];
    }
    __syncthreads();

    int kk = n < K_ ? n : K_;
    for (int t = 0; t < kk; t++) {
        double best = 1e300; int bi = -1;
        for (int i = tid; i < n; i += 256)
            if (d2s[i] < best) { best = d2s[i]; bi = i; }
        red[tid] = best; redi[tid] = bi;
        __syncthreads();
        for (int s = 128; s > 0; s >>= 1) {
            if (tid < s && red[tid+s] < red[tid]) { red[tid] = red[tid+s]; redi[tid] = redi[tid+s]; }
            __syncthreads();
        }
        if (tid == 0) {
            int wi = redi[0];
            double d = d2s[wi]; if (d < 0.0) d = 0.0;
            double wgt = 1.0 / (d + DELTA);
            acc_w += wgt; acc_wv += wgt * (double)vs[wi];
            d2s[wi] = 2e300;
        }
        __syncthreads();
    }
    if (tid == 0) {
        double v = acc_wv / acc_w;
        out_values[p] = (float)v;
        val64[p] = v;
    }
}

__global__ void argmax_kernel(const double* __restrict__ val64, float* __restrict__ out)
{
    int b = blockIdx.x*blockDim.x + threadIdx.x;
    if (b >= B_) return;
    double v0 = val64[b*A_+0], v1 = val64[b*A_+1], v2 = val64[b*A_+2];
    int bi = 0; double bv = v0;
    if (v1 > bv) { bv = v1; bi = 1; }
    if (v2 > bv) { bv = v2; bi = 2; }
    out[B_*A_ + b] = (float)bi;
}

// ============ host ============
extern "C" void kernel_launch(void* const* d_in, const int* in_sizes, int n_in,
                              void* d_out, int out_size, void* d_ws, size_t ws_size,
                              hipStream_t stream)
{
    const float* x    = (const float*)d_in[0];
    const float* W1   = (const float*)d_in[1];
    const float* b1   = (const float*)d_in[2];
    const float* W2   = (const float*)d_in[3];
    const float* b2   = (const float*)d_in[4];
    const float* W3   = (const float*)d_in[5];
    const float* b3   = (const float*)d_in[6];
    const float* W4   = (const float*)d_in[7];
    const float* b4   = (const float*)d_in[8];
    const float* keys = (const float*)d_in[9];
    const float* memv = (const float*)d_in[10];

    char* ws = (char*)d_ws;

    if (ws_size >= NEED_A) {
        // -------- Path A: MFMA GEMM + u8 bin matrix --------
        double*         h64  = (double*)        (ws + AOFF_H64);
        float*          h32  = (float*)         (ws + AOFF_H32);
        unsigned short* hbf  = (unsigned short*)(ws + AOFF_HBF);
        float*          q2   = (float*)         (ws + AOFF_Q2);
        unsigned*       hist = (unsigned*)      (ws + AOFF_HIST);
        unsigned*       cnt  = (unsigned*)      (ws + AOFF_CNT);
        int*            taub = (int*)           (ws + AOFF_TAUB);
        double*         v64  = (double*)        (ws + AOFF_V64);
        int*            cand = (int*)           (ws + AOFF_CAND);
        unsigned char*  bins = (unsigned char*) (ws + AOFF_BINS);

        hipMemsetAsync(ws + AOFF_HIST, 0, (AOFF_CNT + B_*A_*4) - AOFF_HIST, stream);

        mlp_kernel<<<B_, 128, 0, stream>>>(x, W1, b1, W2, b2, W3, b3, W4, b4, h32, hbf, h64, q2);
        gemm_bin_kernel<<<dim3(NSEG_G, 4, A_), 256, 0, stream>>>(keys, hbf, q2, bins);
        histA_kernel<<<dim3(B_*A_, HSEG), 256, 0, stream>>>(bins, hist);
        tauA_kernel<<<(B_*A_ + 255)/256, 256, 0, stream>>>(hist, taub);
        collectA_kernel<<<dim3(B_*A_, HSEG), 256, 0, stream>>>(bins, taub, cnt, cand);
        select_kernel<<<B_*A_, 256, 0, stream>>>(keys, h64, memv, cnt, cand, (float*)d_out, v64, CAP_A);
        argmax_kernel<<<2, 256, 0, stream>>>(v64, (float*)d_out);
    } else {
        // -------- Path B: round-1 proven fp32 two-pass --------
        float*          h32  = (float*)         (ws + BOFF_H32);
        double*         h64  = (double*)        (ws + BOFF_H64);
        float*          q2   = (float*)         (ws + BOFF_Q2);
        float*          k2   = (float*)         (ws + BOFF_K2);
        unsigned*       hist = (unsigned*)      (ws + BOFF_HIST);
        float*          tau  = (float*)         (ws + BOFF_TAU);
        unsigned*       cnt  = (unsigned*)      (ws + BOFF_CNT);
        double*         v64  = (double*)        (ws + BOFF_V64);
        int*            cand = (int*)           (ws + BOFF_CAND);
        unsigned short* hbf  = (unsigned short*)(ws + BOFF_CAND); // scratch, unused in B

        hipMemsetAsync(ws + BOFF_HIST, 0, (BOFF_CNT + B_*A_*4) - BOFF_HIST, stream);

        mlp_kernel<<<B_, 128, 0, stream>>>(x, W1, b1, W2, b2, W3, b3, W4, b4, h32, hbf, h64, q2);
        k2_kernel<<<(A_*C_)/4, 256, 0, stream>>>(keys, k2);
        pass_kernel<0><<<dim3(B_/BM_B, NCH_B, A_), 256, 0, stream>>>(keys, h32, q2, k2, hist, nullptr, nullptr, nullptr);
        tauB_kernel<<<(B_*A_ + 255)/256, 256, 0, stream>>>(hist, tau);
        pass_kernel<1><<<dim3(B_/BM_B, NCH_B, A_), 256, 0, stream>>>(keys, h32, q2, k2, nullptr, tau, cnt, cand);
        select_kernel<<<B_*A_, 256, 0, stream>>>(keys, h64, memv, cnt, cand, (float*)d_out, v64, CAP_B);
        argmax_kernel<<<2, 256, 0, stream>>>(v64, (float*)d_out);
    }
}